// Round 10
// baseline (309.505 us; speedup 1.0000x reference)
//
#include <hip/hip_runtime.h>
#include <hip/hip_bf16.h>

#define DEV __device__ __forceinline__

typedef unsigned short u16;
typedef unsigned int u32;
typedef __bf16 bf16x8 __attribute__((ext_vector_type(8)));
typedef float f32x4 __attribute__((ext_vector_type(4)));

static constexpr int S   = 2048;
static constexpr int D   = 1024;
static constexpr int H   = 16;
static constexpr int Dh  = 64;
static constexpr int B_  = 4;
static constexpr int M   = B_ * S;   // 8192 tokens

DEV u16 f2bf(float f) {
    __hip_bfloat16 h = __float2bfloat16(f);
    union { __hip_bfloat16 h; u16 u; } cv; cv.h = h; return cv.u;
}
DEV float bf2f(u16 u) {
    union { u16 u; __hip_bfloat16 h; } cv; cv.u = u; return __bfloat162float(cv.h);
}
DEV f32x4 mfma16(bf16x8 a, bf16x8 b, f32x4 c) {
    return __builtin_amdgcn_mfma_f32_16x16x32_bf16(a, b, c, 0, 0, 0);
}
// async global->LDS, 16B per lane; lds dest = wave-uniform base + lane*16
DEV void llds16(const u16* g, u16* l) {
    __builtin_amdgcn_global_load_lds(
        (const __attribute__((address_space(1))) u32*)g,
        (__attribute__((address_space(3))) u32*)l, 16, 0, 0);
}
// load 8 contiguous fp32, round to 8 bf16
DEV bf16x8 ld8f(const float* p) {
    const f32x4* q = reinterpret_cast<const f32x4*>(p);
    f32x4 a = q[0], b = q[1];
    union { u16 u[8]; bf16x8 v; } r;
    r.u[0] = f2bf(a[0]); r.u[1] = f2bf(a[1]); r.u[2] = f2bf(a[2]); r.u[3] = f2bf(a[3]);
    r.u[4] = f2bf(b[0]); r.u[5] = f2bf(b[1]); r.u[6] = f2bf(b[2]); r.u[7] = f2bf(b[3]);
    return r.v;
}

// ---------------------------------------------------------------------------
// x fp32 -> bf16 (one-shot)
// ---------------------------------------------------------------------------
__global__ __launch_bounds__(256) void x_to_bf16(
    const float* __restrict__ x, u16* __restrict__ xb)
{
    size_t i = ((size_t)blockIdx.x * 256 + threadIdx.x) * 8;
    *reinterpret_cast<bf16x8*>(xb + i) = ld8f(x + i);
}

// ---------------------------------------------------------------------------
// Transpose + bf16-convert the 4 fp32 weight matrices [K][N] -> bf16 [N][K]
// ---------------------------------------------------------------------------
__global__ __launch_bounds__(256) void transpose_w(
    const float* __restrict__ Wq, const float* __restrict__ Wk,
    const float* __restrict__ Wv, const float* __restrict__ Wo,
    u16* __restrict__ WT)
{
    const float* src = blockIdx.z == 0 ? Wq : blockIdx.z == 1 ? Wk
                     : blockIdx.z == 2 ? Wv : Wo;
    u16* dst = WT + (size_t)blockIdx.z * D * D;
    __shared__ u16 T[64 * 72];
    const int k0 = blockIdx.x * 64, n0 = blockIdx.y * 64;
    const int tid = threadIdx.x;
    for (int c = tid; c < 512; c += 256) {
        int r = c >> 3, cc = (c & 7) << 3;
        *reinterpret_cast<bf16x8*>(&T[r * 72 + cc]) =
            ld8f(&src[(size_t)(k0 + r) * D + n0 + cc]);
    }
    __syncthreads();
    for (int c = tid; c < 512; c += 256) {
        int r = c >> 3, cc = (c & 7) << 3;
        u16 tmp[8];
        #pragma unroll
        for (int i = 0; i < 8; ++i) tmp[i] = T[(cc + i) * 72 + r];
        *reinterpret_cast<bf16x8*>(&dst[(size_t)(n0 + r) * D + k0 + cc]) =
            *reinterpret_cast<const bf16x8*>(tmp);
    }
}

// ---------------------------------------------------------------------------
// 128x128 GEMM, BK=64 (16 K-iters, half the barriers of BK=32).
// Staging LDS stride = 64 u16 = 128 B -> chunk-XOR swizzle (same scheme as
// attn round 7) keeps fragment ds_read_b128 bank-clean.
// Q/K: coalesced stores via LDS repack. V: LDS transpose -> Vt [bh][dh][s].
// ---------------------------------------------------------------------------
__global__ __launch_bounds__(256) void qkv_gemm128(
    const u16* __restrict__ A, const u16* __restrict__ WT,
    u16* __restrict__ qkv, u16* __restrict__ vtb)
{
    const int bm = blockIdx.x;     // 0..63
    const int bn = blockIdx.y;     // 0..23

    __shared__ u16 SB[16384];      // staging 2x8192 u16 (32 KB); repack 8704 reuse
    u16* As = SB;
    u16* Bs = SB + 8192;

    const int tid  = threadIdx.x;
    const int wave = tid >> 6, ln = tid & 63;
    const int ln15 = ln & 15, quad = ln >> 4;
    const int swz  = ln15 & 7;
    const int wm = (wave >> 1) * 64, wn = (wave & 1) * 64;

    const u16* Ab = A  + (size_t)(bm * 128) * D;
    const u16* Bb = WT + (size_t)(bn * 128) * D;

    // staging chunk coords: 4 calls/matrix/wave; chunk ch = wave*256+k*64+ln
    int srow[4], soff[4];
    #pragma unroll
    for (int k = 0; k < 4; ++k) {
        int ch = wave * 256 + k * 64 + ln;
        srow[k] = ch >> 3;
        soff[k] = ((ch & 7) ^ (srow[k] & 7)) * 8;
    }

    f32x4 acc[4][4] = {};

    for (int k0 = 0; k0 < D; k0 += 64) {
        __syncthreads();
        #pragma unroll
        for (int k = 0; k < 4; ++k) {
            llds16(Ab + (size_t)srow[k] * D + k0 + soff[k], &As[(wave * 4 + k) * 512]);
            llds16(Bb + (size_t)srow[k] * D + k0 + soff[k], &Bs[(wave * 4 + k) * 512]);
        }
        __syncthreads();
        #pragma unroll
        for (int ks = 0; ks < 2; ++ks) {
            bf16x8 af[4], bfr[4];
            #pragma unroll
            for (int i = 0; i < 4; ++i)
                af[i] = *reinterpret_cast<const bf16x8*>(
                    &As[(wm + i * 16 + ln15) * 64 + ((ks * 4 + quad) ^ swz) * 8]);
            #pragma unroll
            for (int j = 0; j < 4; ++j)
                bfr[j] = *reinterpret_cast<const bf16x8*>(
                    &Bs[(wn + j * 16 + ln15) * 64 + ((ks * 4 + quad) ^ swz) * 8]);
            #pragma unroll
            for (int i = 0; i < 4; ++i)
                #pragma unroll
                for (int j = 0; j < 4; ++j)
                    acc[i][j] = mfma16(af[i], bfr[j], acc[i][j]);
        }
    }

    const int matn = bn >> 3;      // 0=Q 1=K 2=V (block-uniform)
    const int t0 = bm * 128, b = t0 >> 11, s0 = t0 & (S - 1);
    __syncthreads();               // all waves done reading staging SB

    if (matn < 2) {
        u16* outp = qkv + (size_t)matn * M * D;
        #pragma unroll
        for (int h2 = 0; h2 < 2; ++h2) {    // half-tile: rows h2*64..h2*64+63
            if ((wave >> 1) == h2) {
                #pragma unroll
                for (int i = 0; i < 4; ++i)
                    #pragma unroll
                    for (int j = 0; j < 4; ++j)
                        #pragma unroll
                        for (int r = 0; r < 4; ++r)
                            SB[(i * 16 + quad * 4 + r) * 136 + wn + j * 16 + ln15] =
                                f2bf(acc[i][j][r]);
            }
            __syncthreads();
            for (int c = tid; c < 1024; c += 256) {
                int r = c >> 4, cc = (c & 15) * 8;
                int head = (bn & 7) * 2 + (cc >> 6);
                int s = s0 + h2 * 64 + r;
                *reinterpret_cast<bf16x8*>(
                    &outp[(((size_t)(b * H + head)) * S + s) * Dh + (cc & 63)]) =
                    *reinterpret_cast<const bf16x8*>(&SB[r * 136 + cc]);
            }
            __syncthreads();
        }
    } else {
        // V: per-head LDS transpose -> Vt [bh][dh][s]
        #pragma unroll
        for (int h2 = 0; h2 < 2; ++h2) {
            if ((wave & 1) == h2) {
                #pragma unroll
                for (int i = 0; i < 4; ++i)
                    #pragma unroll
                    for (int j = 0; j < 4; ++j)
                        #pragma unroll
                        for (int r = 0; r < 4; ++r) {
                            int sl = wm + i * 16 + quad * 4 + r;   // 0..127
                            int dh = j * 16 + ln15;                // 0..63
                            SB[dh * 136 + sl] = f2bf(acc[i][j][r]);
                        }
            }
            __syncthreads();
            const int bh = b * H + (bn & 7) * 2 + h2;
            u16* dst = vtb + (size_t)bh * Dh * S + s0;
            for (int c = tid; c < 1024; c += 256) {
                int r = c >> 4, cc = (c & 15) * 8;
                *reinterpret_cast<bf16x8*>(&dst[(size_t)r * S + cc]) =
                    *reinterpret_cast<const bf16x8*>(&SB[r * 136 + cc]);
            }
            __syncthreads();
        }
    }
}

// ---------------------------------------------------------------------------
// Flash attention (causal). 4 q-tiles/block {i,15-i,16+i,31-i}, grid 8x64
// (round-8 best config: steps/stage 2.3 is the amortization lever; round 9's
// 2-tile/1024-block split regressed via +72% staging).
// Double-buffered K/V + register-hoisted fragments. Fixed-offset softmax:
// QK acc init -24, p=2^s, unnormalized O, one epilogue reduce.
// K/V and P chunk-XOR-swizzled (conflicts 20.5M -> ~0.2M).
// ---------------------------------------------------------------------------
__global__ __launch_bounds__(256) void attn_kernel(
    const u16* __restrict__ qbuf, const u16* __restrict__ kbuf,
    const u16* __restrict__ vt, u16* __restrict__ attno)
{
    const int i  = blockIdx.x;          // 0..7
    const int bh = blockIdx.y;          // 0..63
    const int b = bh >> 4, h = bh & 15;
    const int qt[4] = {i, 15 - i, 16 + i, 31 - i};

    __shared__ u16 Ks[2][64 * 64];
    __shared__ u16 Vs[2][64 * 64];      // [dh][kpos], chunk-swizzled
    __shared__ u16 Ps[4][16 * 64];      // per-wave P tile, chunk-swizzled

    const int tid  = threadIdx.x;
    const int wave = tid >> 6, ln = tid & 63;
    const int ln15 = ln & 15, quad = ln >> 4;
    const int swz  = ln15 & 7;

    const u16* kp0 = kbuf + (size_t)bh * S * Dh;
    const u16* vp0 = vt   + (size_t)bh * Dh * S;

    // Q fragments for all 4 tiles, pre-scaled by 0.125*log2e (Ks[0] scratch)
    bf16x8 qf[4][2];
    #pragma unroll
    for (int t = 0; t < 4; ++t) {
        const u16* qp = qbuf + ((size_t)bh * S + qt[t] * 64) * Dh;
        for (int c = tid; c < 512; c += 256) {
            int r = c >> 3, cc = (c & 7) << 3;
            *reinterpret_cast<bf16x8*>(&Ks[0][r * 64 + cc]) =
                *reinterpret_cast<const bf16x8*>(&qp[r * 64 + cc]);
        }
        __syncthreads();
        #pragma unroll
        for (int st = 0; st < 2; ++st) {
            union { bf16x8 v; u16 u[8]; } in, ot;
            in.v = *reinterpret_cast<const bf16x8*>(&Ks[0][(wave * 16 + ln15) * 64 + st * 32 + quad * 8]);
            #pragma unroll
            for (int k = 0; k < 8; ++k) ot.u[k] = f2bf(bf2f(in.u[k]) * 0.18033688f);
            qf[t][st] = ot.v;
        }
        __syncthreads();
    }

    float l_st[4][4] = {};
    f32x4 o_st[4][4] = {};

    u16* psw = &Ps[wave][0];
    const int lrow = wave * 16 + quad * 4;

    const int c0 = wave * 128 + ln;
    const int c1 = c0 + 64;
    const int kr0 = c0 >> 3, ko0 = (((c0 & 7) ^ (kr0 & 7)) * 8);
    const int kr1 = c1 >> 3, ko1 = (((c1 & 7) ^ (kr1 & 7)) * 8);

    auto stage = [&](int kblk, int buf) {
        llds16(kp0 + ((size_t)kblk * 64 + kr0) * Dh + ko0, &Ks[buf][(wave * 2 + 0) * 512]);
        llds16(kp0 + ((size_t)kblk * 64 + kr1) * Dh + ko1, &Ks[buf][(wave * 2 + 1) * 512]);
        llds16(vp0 + (size_t)kr0 * S + kblk * 64 + ko0,    &Vs[buf][(wave * 2 + 0) * 512]);
        llds16(vp0 + (size_t)kr1 * S + kblk * 64 + ko1,    &Vs[buf][(wave * 2 + 1) * 512]);
    };

    bf16x8 kf[2][4], vf[2][4];

    auto step = [&](int t, bool domask) {
        const bf16x8* qa = qf[t];
        float* l_r = l_st[t];
        f32x4* oa = o_st[t];
        const f32x4 minit = {-24.f, -24.f, -24.f, -24.f};
        f32x4 sf[4] = {minit, minit, minit, minit};
        #pragma unroll
        for (int j = 0; j < 4; ++j) {
            sf[j] = mfma16(qa[0], kf[0][j], sf[j]);
            sf[j] = mfma16(qa[1], kf[1][j], sf[j]);
        }
        if (domask) {
            #pragma unroll
            for (int j = 0; j < 4; ++j) {
                int kg = j * 16 + ln15;
                #pragma unroll
                for (int r = 0; r < 4; ++r)
                    if (kg > lrow + r) sf[j][r] = -3e38f;
            }
        }
        #pragma unroll
        for (int j = 0; j < 4; ++j)
            #pragma unroll
            for (int r = 0; r < 4; ++r) {
                float p = exp2f(sf[j][r]);
                sf[j][r] = p;
                l_r[r] += p;
            }
        // P: C-layout regs -> per-wave swizzled LDS -> A-layout frags
        #pragma unroll
        for (int j = 0; j < 4; ++j)
            #pragma unroll
            for (int r = 0; r < 4; ++r) {
                int q = quad * 4 + r;
                int phys = ((j * 2 + (ln15 >> 3)) ^ (q & 7)) * 8 + (ln15 & 7);
                psw[q * 64 + phys] = f2bf(sf[j][r]);
            }

        #pragma unroll
        for (int st = 0; st < 2; ++st) {
            bf16x8 pa = *reinterpret_cast<const bf16x8*>(
                &psw[ln15 * 64 + ((st * 4 + quad) ^ swz) * 8]);
            #pragma unroll
            for (int jd = 0; jd < 4; ++jd)
                oa[jd] = mfma16(pa, vf[st][jd], oa[jd]);
        }
    };

    const int nstage = qt[3] + 1;       // 32 - i
    stage(0, 0);
    int cur = 0;
    for (int kblk = 0; kblk < nstage; ++kblk) {
        __syncthreads();                     // drains prefetch for cur buffer
        if (kblk + 1 < nstage) stage(kblk + 1, cur ^ 1);
        #pragma unroll
        for (int st = 0; st < 2; ++st)
            #pragma unroll
            for (int j = 0; j < 4; ++j) {
                kf[st][j] = *reinterpret_cast<const bf16x8*>(
                    &Ks[cur][(j * 16 + ln15) * 64 + ((st * 4 + quad) ^ swz) * 8]);
                vf[st][j] = *reinterpret_cast<const bf16x8*>(
                    &Vs[cur][(j * 16 + ln15) * 64 + ((st * 4 + quad) ^ swz) * 8]);
            }
        step(3, kblk == qt[3]);
        if (kblk <= qt[2]) step(2, kblk == qt[2]);
        if (kblk <= qt[1]) step(1, kblk == qt[1]);
        if (kblk <= qt[0]) step(0, kblk == qt[0]);
        cur ^= 1;
    }

    // epilogue: reduce l over the 16 column-lanes, divide, write token-major
    #pragma unroll
    for (int t = 0; t < 4; ++t) {
        float linv[4];
        #pragma unroll
        for (int r = 0; r < 4; ++r) {
            float l = l_st[t][r];
            l += __shfl_xor(l, 1, 64);
            l += __shfl_xor(l, 2, 64);
            l += __shfl_xor(l, 4, 64);
            l += __shfl_xor(l, 8, 64);
            linv[r] = 1.0f / l;
        }
        #pragma unroll
        for (int jd = 0; jd < 4; ++jd)
            #pragma unroll
            for (int r = 0; r < 4; ++r) {
                int qrow = qt[t] * 64 + wave * 16 + quad * 4 + r;
                size_t off = ((size_t)(b * S + qrow)) * D + h * Dh + jd * 16 + ln15;
                attno[off] = f2bf(o_st[t][jd][r] * linv[r]);
            }
    }
}

// ---------------------------------------------------------------------------
// 128x128 projection GEMM + bias, BK=64, swizzled staging: -> fp32 d_out
// ---------------------------------------------------------------------------
__global__ __launch_bounds__(256) void proj_gemm128(
    const u16* __restrict__ A, const u16* __restrict__ WoT,
    const float* __restrict__ bo, float* __restrict__ out)
{
    const int bm = blockIdx.x;     // 0..63
    const int bn = blockIdx.y;     // 0..7

    __shared__ u16 As[8192];
    __shared__ u16 Bs[8192];

    const int tid  = threadIdx.x;
    const int wave = tid >> 6, ln = tid & 63;
    const int ln15 = ln & 15, quad = ln >> 4;
    const int swz  = ln15 & 7;
    const int wm = (wave >> 1) * 64, wn = (wave & 1) * 64;

    const u16* Ab = A   + (size_t)(bm * 128) * D;
    const u16* Bb = WoT + (size_t)(bn * 128) * D;

    int srow[4], soff[4];
    #pragma unroll
    for (int k = 0; k < 4; ++k) {
        int ch = wave * 256 + k * 64 + ln;
        srow[k] = ch >> 3;
        soff[k] = ((ch & 7) ^ (srow[k] & 7)) * 8;
    }

    f32x4 acc[4][4] = {};

    for (int k0 = 0; k0 < D; k0 += 64) {
        __syncthreads();
        #pragma unroll
        for (int k = 0; k < 4; ++k) {
            llds16(Ab + (size_t)srow[k] * D + k0 + soff[k], &As[(wave * 4 + k) * 512]);
            llds16(Bb + (size_t)srow[k] * D + k0 + soff[k], &Bs[(wave * 4 + k) * 512]);
        }
        __syncthreads();
        #pragma unroll
        for (int ks = 0; ks < 2; ++ks) {
            bf16x8 af[4], bfr[4];
            #pragma unroll
            for (int i = 0; i < 4; ++i)
                af[i] = *reinterpret_cast<const bf16x8*>(
                    &As[(wm + i * 16 + ln15) * 64 + ((ks * 4 + quad) ^ swz) * 8]);
            #pragma unroll
            for (int j = 0; j < 4; ++j)
                bfr[j] = *reinterpret_cast<const bf16x8*>(
                    &Bs[(wn + j * 16 + ln15) * 64 + ((ks * 4 + quad) ^ swz) * 8]);
            #pragma unroll
            for (int i = 0; i < 4; ++i)
                #pragma unroll
                for (int j = 0; j < 4; ++j)
                    acc[i][j] = mfma16(af[i], bfr[j], acc[i][j]);
        }
    }

    #pragma unroll
    for (int i = 0; i < 4; ++i)
        #pragma unroll
        for (int j = 0; j < 4; ++j)
            #pragma unroll
            for (int r = 0; r < 4; ++r) {
                int t   = bm * 128 + wm + i * 16 + quad * 4 + r;
                int col = bn * 128 + wn + j * 16 + ln15;
                out[(size_t)t * D + col] = acc[i][j][r] + bo[col];
            }
}

extern "C" void kernel_launch(void* const* d_in, const int* in_sizes, int n_in,
                              void* d_out, int out_size, void* d_ws, size_t ws_size,
                              hipStream_t stream) {
    const float* x  = (const float*)d_in[0];
    const float* Wq = (const float*)d_in[1];
    const float* Wk = (const float*)d_in[2];
    const float* Wv = (const float*)d_in[3];
    const float* Wo = (const float*)d_in[4];
    const float* bo = (const float*)d_in[5];
    float* out = (float*)d_out;
    u16* ws  = (u16*)d_ws;

    u16* WT   = ws;                                   // 4M u16  (8 MB)
    u16* xb   = WT + (size_t)4 * D * D;               // 8M u16  (16 MB)
    u16* qkvb = xb + (size_t)M * D;                   // slots: Q, K, Vt (48 MB)
    u16* kb   = qkvb + (size_t)M * D;
    u16* vtb  = qkvb + (size_t)2 * M * D;             // V written transposed here
    u16* attn = xb;                                   // xb dead after qkv_gemm128

    x_to_bf16   <<<dim3(M * D / (256 * 8)), 256, 0, stream>>>(x, xb);
    transpose_w <<<dim3(16, 16, 4), 256, 0, stream>>>(Wq, Wk, Wv, Wo, WT);
    qkv_gemm128 <<<dim3(64, 24),    256, 0, stream>>>(xb, WT, qkvb, vtb);
    attn_kernel <<<dim3(8, 64),     256, 0, stream>>>(qkvb, kb, vtb, attn);
    proj_gemm128<<<dim3(64, 8),     256, 0, stream>>>(attn, WT + (size_t)3 * D * D, bo, out);
}

// Round 11
// 268.991 us; speedup vs baseline: 1.1506x; 1.1506x over previous
//
#include <hip/hip_runtime.h>
#include <hip/hip_bf16.h>

#define DEV __device__ __forceinline__

typedef unsigned short u16;
typedef unsigned int u32;
typedef __bf16 bf16x8 __attribute__((ext_vector_type(8)));
typedef float f32x4 __attribute__((ext_vector_type(4)));

static constexpr int S   = 2048;
static constexpr int D   = 1024;
static constexpr int H   = 16;
static constexpr int Dh  = 64;
static constexpr int B_  = 4;
static constexpr int M   = B_ * S;   // 8192 tokens

DEV u16 f2bf(float f) {
    __hip_bfloat16 h = __float2bfloat16(f);
    union { __hip_bfloat16 h; u16 u; } cv; cv.h = h; return cv.u;
}
DEV float bf2f(u16 u) {
    union { u16 u; __hip_bfloat16 h; } cv; cv.u = u; return __bfloat162float(cv.h);
}
DEV f32x4 mfma16(bf16x8 a, bf16x8 b, f32x4 c) {
    return __builtin_amdgcn_mfma_f32_16x16x32_bf16(a, b, c, 0, 0, 0);
}
// async global->LDS, 16B per lane; lds dest = wave-uniform base + lane*16
DEV void llds16(const u16* g, u16* l) {
    __builtin_amdgcn_global_load_lds(
        (const __attribute__((address_space(1))) u32*)g,
        (__attribute__((address_space(3))) u32*)l, 16, 0, 0);
}
// load 8 contiguous fp32, round to 8 bf16
DEV bf16x8 ld8f(const float* p) {
    const f32x4* q = reinterpret_cast<const f32x4*>(p);
    f32x4 a = q[0], b = q[1];
    union { u16 u[8]; bf16x8 v; } r;
    r.u[0] = f2bf(a[0]); r.u[1] = f2bf(a[1]); r.u[2] = f2bf(a[2]); r.u[3] = f2bf(a[3]);
    r.u[4] = f2bf(b[0]); r.u[5] = f2bf(b[1]); r.u[6] = f2bf(b[2]); r.u[7] = f2bf(b[3]);
    return r.v;
}

// ---------------------------------------------------------------------------
// prep: fused (a) transpose+bf16-convert of the 4 weight matrices (z=0..3)
// and (b) x fp32->bf16 convert (z=4..19). Branch is block-uniform.
// ---------------------------------------------------------------------------
__global__ __launch_bounds__(256) void prep(
    const float* __restrict__ x,
    const float* __restrict__ Wq, const float* __restrict__ Wk,
    const float* __restrict__ Wv, const float* __restrict__ Wo,
    u16* __restrict__ WT, u16* __restrict__ xb)
{
    const int z = blockIdx.z;
    const int tid = threadIdx.x;
    __shared__ u16 T[64 * 72];
    if (z < 4) {
        const float* src = z == 0 ? Wq : z == 1 ? Wk : z == 2 ? Wv : Wo;
        u16* dst = WT + (size_t)z * D * D;
        const int k0 = blockIdx.x * 64, n0 = blockIdx.y * 64;
        for (int c = tid; c < 512; c += 256) {
            int r = c >> 3, cc = (c & 7) << 3;
            *reinterpret_cast<bf16x8*>(&T[r * 72 + cc]) =
                ld8f(&src[(size_t)(k0 + r) * D + n0 + cc]);
        }
        __syncthreads();
        for (int c = tid; c < 512; c += 256) {
            int r = c >> 3, cc = (c & 7) << 3;
            u16 tmp[8];
            #pragma unroll
            for (int i = 0; i < 8; ++i) tmp[i] = T[(cc + i) * 72 + r];
            *reinterpret_cast<bf16x8*>(&dst[(size_t)(n0 + r) * D + k0 + cc]) =
                *reinterpret_cast<const bf16x8*>(tmp);
        }
    } else {
        size_t lin = ((size_t)(z - 4) * 256 + blockIdx.y * 16 + blockIdx.x);
        size_t i = (lin * 256 + tid) * 8;
        *reinterpret_cast<bf16x8*>(xb + i) = ld8f(x + i);
    }
}

// ---------------------------------------------------------------------------
// 128x128 GEMM, BK=64 (16 K-iters; measured ~10us faster than BK=32 in r10).
// Staging stride 64 u16 = 128 B -> chunk-XOR swizzle keeps ds_read_b128
// bank-clean. Q/K: coalesced stores via LDS repack. V: LDS transpose -> Vt.
// ---------------------------------------------------------------------------
__global__ __launch_bounds__(256) void qkv_gemm128(
    const u16* __restrict__ A, const u16* __restrict__ WT,
    u16* __restrict__ qkv, u16* __restrict__ vtb)
{
    const int bm = blockIdx.x;     // 0..63
    const int bn = blockIdx.y;     // 0..23

    __shared__ u16 SB[16384];      // staging 2x8192 u16 (32 KB); repack reuse
    u16* As = SB;
    u16* Bs = SB + 8192;

    const int tid  = threadIdx.x;
    const int wave = tid >> 6, ln = tid & 63;
    const int ln15 = ln & 15, quad = ln >> 4;
    const int swz  = ln15 & 7;
    const int wm = (wave >> 1) * 64, wn = (wave & 1) * 64;

    const u16* Ab = A  + (size_t)(bm * 128) * D;
    const u16* Bb = WT + (size_t)(bn * 128) * D;

    int srow[4], soff[4];
    #pragma unroll
    for (int k = 0; k < 4; ++k) {
        int ch = wave * 256 + k * 64 + ln;
        srow[k] = ch >> 3;
        soff[k] = ((ch & 7) ^ (srow[k] & 7)) * 8;
    }

    f32x4 acc[4][4] = {};

    for (int k0 = 0; k0 < D; k0 += 64) {
        __syncthreads();
        #pragma unroll
        for (int k = 0; k < 4; ++k) {
            llds16(Ab + (size_t)srow[k] * D + k0 + soff[k], &As[(wave * 4 + k) * 512]);
            llds16(Bb + (size_t)srow[k] * D + k0 + soff[k], &Bs[(wave * 4 + k) * 512]);
        }
        __syncthreads();
        #pragma unroll
        for (int ks = 0; ks < 2; ++ks) {
            bf16x8 af[4], bfr[4];
            #pragma unroll
            for (int i = 0; i < 4; ++i)
                af[i] = *reinterpret_cast<const bf16x8*>(
                    &As[(wm + i * 16 + ln15) * 64 + ((ks * 4 + quad) ^ swz) * 8]);
            #pragma unroll
            for (int j = 0; j < 4; ++j)
                bfr[j] = *reinterpret_cast<const bf16x8*>(
                    &Bs[(wn + j * 16 + ln15) * 64 + ((ks * 4 + quad) ^ swz) * 8]);
            #pragma unroll
            for (int i = 0; i < 4; ++i)
                #pragma unroll
                for (int j = 0; j < 4; ++j)
                    acc[i][j] = mfma16(af[i], bfr[j], acc[i][j]);
        }
    }

    const int matn = bn >> 3;      // 0=Q 1=K 2=V (block-uniform)
    const int t0 = bm * 128, b = t0 >> 11, s0 = t0 & (S - 1);
    __syncthreads();               // all waves done reading staging SB

    if (matn < 2) {
        u16* outp = qkv + (size_t)matn * M * D;
        #pragma unroll
        for (int h2 = 0; h2 < 2; ++h2) {
            if ((wave >> 1) == h2) {
                #pragma unroll
                for (int i = 0; i < 4; ++i)
                    #pragma unroll
                    for (int j = 0; j < 4; ++j)
                        #pragma unroll
                        for (int r = 0; r < 4; ++r)
                            SB[(i * 16 + quad * 4 + r) * 136 + wn + j * 16 + ln15] =
                                f2bf(acc[i][j][r]);
            }
            __syncthreads();
            for (int c = tid; c < 1024; c += 256) {
                int r = c >> 4, cc = (c & 15) * 8;
                int head = (bn & 7) * 2 + (cc >> 6);
                int s = s0 + h2 * 64 + r;
                *reinterpret_cast<bf16x8*>(
                    &outp[(((size_t)(b * H + head)) * S + s) * Dh + (cc & 63)]) =
                    *reinterpret_cast<const bf16x8*>(&SB[r * 136 + cc]);
            }
            __syncthreads();
        }
    } else {
        #pragma unroll
        for (int h2 = 0; h2 < 2; ++h2) {
            if ((wave & 1) == h2) {
                #pragma unroll
                for (int i = 0; i < 4; ++i)
                    #pragma unroll
                    for (int j = 0; j < 4; ++j)
                        #pragma unroll
                        for (int r = 0; r < 4; ++r) {
                            int sl = wm + i * 16 + quad * 4 + r;   // 0..127
                            int dh = j * 16 + ln15;                // 0..63
                            SB[dh * 136 + sl] = f2bf(acc[i][j][r]);
                        }
            }
            __syncthreads();
            const int bh = b * H + (bn & 7) * 2 + h2;
            u16* dst = vtb + (size_t)bh * Dh * S + s0;
            for (int c = tid; c < 1024; c += 256) {
                int r = c >> 4, cc = (c & 15) * 8;
                *reinterpret_cast<bf16x8*>(&dst[(size_t)r * S + cc]) =
                    *reinterpret_cast<const bf16x8*>(&SB[r * 136 + cc]);
            }
            __syncthreads();
        }
    }
}

// ---------------------------------------------------------------------------
// Flash attention (causal) — EXACT round-8 version (94.5 us measured).
// 4 q-tiles/block {i,15-i,16+i,31-i}, dbuf K/V stages, register-hoisted
// fragments, fixed-offset softmax p=2^(s-24), P stride 72 unswizzled.
// (r10's P-swizzle + acc-init-(-24) variant regressed 40% via occupancy drop
// — do not reintroduce without isolating the cause.)
// ---------------------------------------------------------------------------
__global__ __launch_bounds__(256) void attn_kernel(
    const u16* __restrict__ qbuf, const u16* __restrict__ kbuf,
    const u16* __restrict__ vt, u16* __restrict__ attno)
{
    const int i  = blockIdx.x;          // 0..7
    const int bh = blockIdx.y;          // 0..63
    const int b = bh >> 4, h = bh & 15;
    const int qt[4] = {i, 15 - i, 16 + i, 31 - i};

    __shared__ u16 Ks[2][64 * 64];
    __shared__ u16 Vs[2][64 * 64];      // [dh][kpos], chunk-swizzled
    __shared__ u16 Ps[4][16 * 72];      // per-wave P tile, stride 72

    const int tid  = threadIdx.x;
    const int wave = tid >> 6, ln = tid & 63;
    const int ln15 = ln & 15, quad = ln >> 4;
    const int swz  = ln15 & 7;

    const u16* kp0 = kbuf + (size_t)bh * S * Dh;
    const u16* vp0 = vt   + (size_t)bh * Dh * S;

    // Q fragments for all 4 tiles, pre-scaled by 0.125*log2e (Ks[0] scratch)
    bf16x8 qf[4][2];
    #pragma unroll
    for (int t = 0; t < 4; ++t) {
        const u16* qp = qbuf + ((size_t)bh * S + qt[t] * 64) * Dh;
        for (int c = tid; c < 512; c += 256) {
            int r = c >> 3, cc = (c & 7) << 3;
            *reinterpret_cast<bf16x8*>(&Ks[0][r * 64 + cc]) =
                *reinterpret_cast<const bf16x8*>(&qp[r * 64 + cc]);
        }
        __syncthreads();
        #pragma unroll
        for (int st = 0; st < 2; ++st) {
            union { bf16x8 v; u16 u[8]; } in, ot;
            in.v = *reinterpret_cast<const bf16x8*>(&Ks[0][(wave * 16 + ln15) * 64 + st * 32 + quad * 8]);
            #pragma unroll
            for (int k = 0; k < 8; ++k) ot.u[k] = f2bf(bf2f(in.u[k]) * 0.18033688f);
            qf[t][st] = ot.v;
        }
        __syncthreads();
    }

    float l_st[4][4] = {};
    f32x4 o_st[4][4] = {};

    u16* psw = &Ps[wave][0];
    const int lrow = wave * 16 + quad * 4;

    const int c0 = wave * 128 + ln;
    const int c1 = c0 + 64;
    const int kr0 = c0 >> 3, ko0 = (((c0 & 7) ^ (kr0 & 7)) * 8);
    const int kr1 = c1 >> 3, ko1 = (((c1 & 7) ^ (kr1 & 7)) * 8);

    auto stage = [&](int kblk, int buf) {
        llds16(kp0 + ((size_t)kblk * 64 + kr0) * Dh + ko0, &Ks[buf][(wave * 2 + 0) * 512]);
        llds16(kp0 + ((size_t)kblk * 64 + kr1) * Dh + ko1, &Ks[buf][(wave * 2 + 1) * 512]);
        llds16(vp0 + (size_t)kr0 * S + kblk * 64 + ko0,    &Vs[buf][(wave * 2 + 0) * 512]);
        llds16(vp0 + (size_t)kr1 * S + kblk * 64 + ko1,    &Vs[buf][(wave * 2 + 1) * 512]);
    };

    bf16x8 kf[2][4], vf[2][4];

    auto step = [&](int t, bool domask) {
        const bf16x8* qa = qf[t];
        float* l_r = l_st[t];
        f32x4* oa = o_st[t];
        f32x4 sf[4] = {};
        #pragma unroll
        for (int j = 0; j < 4; ++j) {
            sf[j] = mfma16(qa[0], kf[0][j], sf[j]);
            sf[j] = mfma16(qa[1], kf[1][j], sf[j]);
        }
        if (domask) {
            #pragma unroll
            for (int j = 0; j < 4; ++j) {
                int kg = j * 16 + ln15;
                #pragma unroll
                for (int r = 0; r < 4; ++r)
                    if (kg > lrow + r) sf[j][r] = -3e38f;
            }
        }
        #pragma unroll
        for (int j = 0; j < 4; ++j)
            #pragma unroll
            for (int r = 0; r < 4; ++r) {
                float p = exp2f(sf[j][r] - 24.0f);
                sf[j][r] = p;
                l_r[r] += p;
            }
        #pragma unroll
        for (int j = 0; j < 4; ++j)
            #pragma unroll
            for (int r = 0; r < 4; ++r)
                psw[(quad * 4 + r) * 72 + j * 16 + ln15] = f2bf(sf[j][r]);

        #pragma unroll
        for (int st = 0; st < 2; ++st) {
            bf16x8 pa = *reinterpret_cast<const bf16x8*>(&psw[ln15 * 72 + st * 32 + quad * 8]);
            #pragma unroll
            for (int jd = 0; jd < 4; ++jd)
                oa[jd] = mfma16(pa, vf[st][jd], oa[jd]);
        }
    };

    const int nstage = qt[3] + 1;       // 32 - i
    stage(0, 0);
    int cur = 0;
    for (int kblk = 0; kblk < nstage; ++kblk) {
        __syncthreads();                     // drains prefetch for cur buffer
        if (kblk + 1 < nstage) stage(kblk + 1, cur ^ 1);
        #pragma unroll
        for (int st = 0; st < 2; ++st)
            #pragma unroll
            for (int j = 0; j < 4; ++j) {
                kf[st][j] = *reinterpret_cast<const bf16x8*>(
                    &Ks[cur][(j * 16 + ln15) * 64 + ((st * 4 + quad) ^ swz) * 8]);
                vf[st][j] = *reinterpret_cast<const bf16x8*>(
                    &Vs[cur][(j * 16 + ln15) * 64 + ((st * 4 + quad) ^ swz) * 8]);
            }
        step(3, kblk == qt[3]);
        if (kblk <= qt[2]) step(2, kblk == qt[2]);
        if (kblk <= qt[1]) step(1, kblk == qt[1]);
        if (kblk <= qt[0]) step(0, kblk == qt[0]);
        cur ^= 1;
    }

    // epilogue: reduce l over the 16 column-lanes, divide, write token-major
    #pragma unroll
    for (int t = 0; t < 4; ++t) {
        float linv[4];
        #pragma unroll
        for (int r = 0; r < 4; ++r) {
            float l = l_st[t][r];
            l += __shfl_xor(l, 1, 64);
            l += __shfl_xor(l, 2, 64);
            l += __shfl_xor(l, 4, 64);
            l += __shfl_xor(l, 8, 64);
            linv[r] = 1.0f / l;
        }
        #pragma unroll
        for (int jd = 0; jd < 4; ++jd)
            #pragma unroll
            for (int r = 0; r < 4; ++r) {
                int qrow = qt[t] * 64 + wave * 16 + quad * 4 + r;
                size_t off = ((size_t)(b * S + qrow)) * D + h * Dh + jd * 16 + ln15;
                attno[off] = f2bf(o_st[t][jd][r] * linv[r]);
            }
    }
}

// ---------------------------------------------------------------------------
// 128x128 projection GEMM + bias, BK=64, swizzled staging: -> fp32 d_out
// ---------------------------------------------------------------------------
__global__ __launch_bounds__(256) void proj_gemm128(
    const u16* __restrict__ A, const u16* __restrict__ WoT,
    const float* __restrict__ bo, float* __restrict__ out)
{
    const int bm = blockIdx.x;     // 0..63
    const int bn = blockIdx.y;     // 0..7

    __shared__ u16 As[8192];
    __shared__ u16 Bs[8192];

    const int tid  = threadIdx.x;
    const int wave = tid >> 6, ln = tid & 63;
    const int ln15 = ln & 15, quad = ln >> 4;
    const int swz  = ln15 & 7;
    const int wm = (wave >> 1) * 64, wn = (wave & 1) * 64;

    const u16* Ab = A   + (size_t)(bm * 128) * D;
    const u16* Bb = WoT + (size_t)(bn * 128) * D;

    int srow[4], soff[4];
    #pragma unroll
    for (int k = 0; k < 4; ++k) {
        int ch = wave * 256 + k * 64 + ln;
        srow[k] = ch >> 3;
        soff[k] = ((ch & 7) ^ (srow[k] & 7)) * 8;
    }

    f32x4 acc[4][4] = {};

    for (int k0 = 0; k0 < D; k0 += 64) {
        __syncthreads();
        #pragma unroll
        for (int k = 0; k < 4; ++k) {
            llds16(Ab + (size_t)srow[k] * D + k0 + soff[k], &As[(wave * 4 + k) * 512]);
            llds16(Bb + (size_t)srow[k] * D + k0 + soff[k], &Bs[(wave * 4 + k) * 512]);
        }
        __syncthreads();
        #pragma unroll
        for (int ks = 0; ks < 2; ++ks) {
            bf16x8 af[4], bfr[4];
            #pragma unroll
            for (int i = 0; i < 4; ++i)
                af[i] = *reinterpret_cast<const bf16x8*>(
                    &As[(wm + i * 16 + ln15) * 64 + ((ks * 4 + quad) ^ swz) * 8]);
            #pragma unroll
            for (int j = 0; j < 4; ++j)
                bfr[j] = *reinterpret_cast<const bf16x8*>(
                    &Bs[(wn + j * 16 + ln15) * 64 + ((ks * 4 + quad) ^ swz) * 8]);
            #pragma unroll
            for (int i = 0; i < 4; ++i)
                #pragma unroll
                for (int j = 0; j < 4; ++j)
                    acc[i][j] = mfma16(af[i], bfr[j], acc[i][j]);
        }
    }

    #pragma unroll
    for (int i = 0; i < 4; ++i)
        #pragma unroll
        for (int j = 0; j < 4; ++j)
            #pragma unroll
            for (int r = 0; r < 4; ++r) {
                int t   = bm * 128 + wm + i * 16 + quad * 4 + r;
                int col = bn * 128 + wn + j * 16 + ln15;
                out[(size_t)t * D + col] = acc[i][j][r] + bo[col];
            }
}

extern "C" void kernel_launch(void* const* d_in, const int* in_sizes, int n_in,
                              void* d_out, int out_size, void* d_ws, size_t ws_size,
                              hipStream_t stream) {
    const float* x  = (const float*)d_in[0];
    const float* Wq = (const float*)d_in[1];
    const float* Wk = (const float*)d_in[2];
    const float* Wv = (const float*)d_in[3];
    const float* Wo = (const float*)d_in[4];
    const float* bo = (const float*)d_in[5];
    float* out = (float*)d_out;
    u16* ws  = (u16*)d_ws;

    u16* WT   = ws;                                   // 4M u16  (8 MB)
    u16* xb   = WT + (size_t)4 * D * D;               // 8M u16  (16 MB)
    u16* qkvb = xb + (size_t)M * D;                   // slots: Q, K, Vt (48 MB)
    u16* kb   = qkvb + (size_t)M * D;
    u16* vtb  = qkvb + (size_t)2 * M * D;             // V written transposed here
    u16* attn = xb;                                   // xb dead after qkv_gemm128

    prep        <<<dim3(16, 16, 20), 256, 0, stream>>>(x, Wq, Wk, Wv, Wo, WT, xb);
    qkv_gemm128 <<<dim3(64, 24),     256, 0, stream>>>(xb, WT, qkvb, vtb);
    attn_kernel <<<dim3(8, 64),      256, 0, stream>>>(qkvb, kb, vtb, attn);
    proj_gemm128<<<dim3(64, 8),      256, 0, stream>>>(attn, WT + (size_t)3 * D * D, bo, out);
}

// Round 13
// 263.540 us; speedup vs baseline: 1.1744x; 1.0207x over previous
//
#include <hip/hip_runtime.h>
#include <hip/hip_bf16.h>

#define DEV __device__ __forceinline__

typedef unsigned short u16;
typedef unsigned int u32;
typedef __bf16 bf16x8 __attribute__((ext_vector_type(8)));
typedef float f32x4 __attribute__((ext_vector_type(4)));

static constexpr int S   = 2048;
static constexpr int D   = 1024;
static constexpr int H   = 16;
static constexpr int Dh  = 64;
static constexpr int B_  = 4;
static constexpr int M   = B_ * S;   // 8192 tokens

DEV u16 f2bf(float f) {
    __hip_bfloat16 h = __float2bfloat16(f);
    union { __hip_bfloat16 h; u16 u; } cv; cv.h = h; return cv.u;
}
DEV float bf2f(u16 u) {
    union { u16 u; __hip_bfloat16 h; } cv; cv.u = u; return __bfloat162float(cv.h);
}
DEV f32x4 mfma16(bf16x8 a, bf16x8 b, f32x4 c) {
    return __builtin_amdgcn_mfma_f32_16x16x32_bf16(a, b, c, 0, 0, 0);
}
// async global->LDS, 16B per lane; lds dest = wave-uniform base + lane*16
DEV void llds16(const u16* g, u16* l) {
    __builtin_amdgcn_global_load_lds(
        (const __attribute__((address_space(1))) u32*)g,
        (__attribute__((address_space(3))) u32*)l, 16, 0, 0);
}
// load 8 contiguous fp32, round to 8 bf16
DEV bf16x8 ld8f(const float* p) {
    const f32x4* q = reinterpret_cast<const f32x4*>(p);
    f32x4 a = q[0], b = q[1];
    union { u16 u[8]; bf16x8 v; } r;
    r.u[0] = f2bf(a[0]); r.u[1] = f2bf(a[1]); r.u[2] = f2bf(a[2]); r.u[3] = f2bf(a[3]);
    r.u[4] = f2bf(b[0]); r.u[5] = f2bf(b[1]); r.u[6] = f2bf(b[2]); r.u[7] = f2bf(b[3]);
    return r.v;
}

// ---------------------------------------------------------------------------
// prep: fused (a) transpose+bf16-convert of the 4 weight matrices (z=0..3)
// and (b) x fp32->bf16 convert (z=4..19). Branch is block-uniform.
// ---------------------------------------------------------------------------
__global__ __launch_bounds__(256) void prep(
    const float* __restrict__ x,
    const float* __restrict__ Wq, const float* __restrict__ Wk,
    const float* __restrict__ Wv, const float* __restrict__ Wo,
    u16* __restrict__ WT, u16* __restrict__ xb)
{
    const int z = blockIdx.z;
    const int tid = threadIdx.x;
    __shared__ u16 T[64 * 72];
    if (z < 4) {
        const float* src = z == 0 ? Wq : z == 1 ? Wk : z == 2 ? Wv : Wo;
        u16* dst = WT + (size_t)z * D * D;
        const int k0 = blockIdx.x * 64, n0 = blockIdx.y * 64;
        for (int c = tid; c < 512; c += 256) {
            int r = c >> 3, cc = (c & 7) << 3;
            *reinterpret_cast<bf16x8*>(&T[r * 72 + cc]) =
                ld8f(&src[(size_t)(k0 + r) * D + n0 + cc]);
        }
        __syncthreads();
        for (int c = tid; c < 512; c += 256) {
            int r = c >> 3, cc = (c & 7) << 3;
            u16 tmp[8];
            #pragma unroll
            for (int i = 0; i < 8; ++i) tmp[i] = T[(cc + i) * 72 + r];
            *reinterpret_cast<bf16x8*>(&dst[(size_t)(n0 + r) * D + k0 + cc]) =
                *reinterpret_cast<const bf16x8*>(tmp);
        }
    } else {
        size_t lin = ((size_t)(z - 4) * 256 + blockIdx.y * 16 + blockIdx.x);
        size_t i = (lin * 256 + tid) * 8;
        *reinterpret_cast<bf16x8*>(xb + i) = ld8f(x + i);
    }
}

// ---------------------------------------------------------------------------
// 128x128 GEMM, BK=64, chunk-XOR-swizzled staging (bank-clean ds_read_b128).
// Q/K: one-phase epilogue — full 128x128 repack at STRIDE 136 (>= 128 row
// width + 16B-aligned; r12's stride-72 overlapped rows and corrupted output).
// V: 2-phase LDS transpose -> Vt [bh][dh][s].
// ---------------------------------------------------------------------------
__global__ __launch_bounds__(256) void qkv_gemm128(
    const u16* __restrict__ A, const u16* __restrict__ WT,
    u16* __restrict__ qkv, u16* __restrict__ vtb)
{
    const int bm = blockIdx.x;     // 0..63
    const int bn = blockIdx.y;     // 0..23

    __shared__ u16 SB[128 * 136];  // 17408 u16 (34 KB): staging (2x8192) + repack
    u16* As = SB;
    u16* Bs = SB + 8192;

    const int tid  = threadIdx.x;
    const int wave = tid >> 6, ln = tid & 63;
    const int ln15 = ln & 15, quad = ln >> 4;
    const int swz  = ln15 & 7;
    const int wm = (wave >> 1) * 64, wn = (wave & 1) * 64;

    const u16* Ab = A  + (size_t)(bm * 128) * D;
    const u16* Bb = WT + (size_t)(bn * 128) * D;

    int srow[4], soff[4];
    #pragma unroll
    for (int k = 0; k < 4; ++k) {
        int ch = wave * 256 + k * 64 + ln;
        srow[k] = ch >> 3;
        soff[k] = ((ch & 7) ^ (srow[k] & 7)) * 8;
    }

    f32x4 acc[4][4] = {};

    for (int k0 = 0; k0 < D; k0 += 64) {
        __syncthreads();
        #pragma unroll
        for (int k = 0; k < 4; ++k) {
            llds16(Ab + (size_t)srow[k] * D + k0 + soff[k], &As[(wave * 4 + k) * 512]);
            llds16(Bb + (size_t)srow[k] * D + k0 + soff[k], &Bs[(wave * 4 + k) * 512]);
        }
        __syncthreads();
        #pragma unroll
        for (int ks = 0; ks < 2; ++ks) {
            bf16x8 af[4], bfr[4];
            #pragma unroll
            for (int i = 0; i < 4; ++i)
                af[i] = *reinterpret_cast<const bf16x8*>(
                    &As[(wm + i * 16 + ln15) * 64 + ((ks * 4 + quad) ^ swz) * 8]);
            #pragma unroll
            for (int j = 0; j < 4; ++j)
                bfr[j] = *reinterpret_cast<const bf16x8*>(
                    &Bs[(wn + j * 16 + ln15) * 64 + ((ks * 4 + quad) ^ swz) * 8]);
            #pragma unroll
            for (int i = 0; i < 4; ++i)
                #pragma unroll
                for (int j = 0; j < 4; ++j)
                    acc[i][j] = mfma16(af[i], bfr[j], acc[i][j]);
        }
    }

    const int matn = bn >> 3;      // 0=Q 1=K 2=V (block-uniform)
    const int t0 = bm * 128, b = t0 >> 11, s0 = t0 & (S - 1);
    __syncthreads();               // all waves done reading staging SB

    if (matn < 2) {
        // one-phase repack: full 128x128 tile, stride 136 (272 B, 16B-aligned)
        u16* outp = qkv + (size_t)matn * M * D;
        #pragma unroll
        for (int i = 0; i < 4; ++i)
            #pragma unroll
            for (int j = 0; j < 4; ++j)
                #pragma unroll
                for (int r = 0; r < 4; ++r)
                    SB[(wm + i * 16 + quad * 4 + r) * 136 + wn + j * 16 + ln15] =
                        f2bf(acc[i][j][r]);
        __syncthreads();
        #pragma unroll
        for (int k = 0; k < 8; ++k) {
            int c = k * 256 + tid;             // 0..2047
            int row = c >> 4, cc = (c & 15) * 8;
            int head = (bn & 7) * 2 + (cc >> 6);
            int s = s0 + row;
            *reinterpret_cast<bf16x8*>(
                &outp[(((size_t)(b * H + head)) * S + s) * Dh + (cc & 63)]) =
                *reinterpret_cast<const bf16x8*>(&SB[row * 136 + cc]);
        }
    } else {
        // V: per-head LDS transpose -> Vt [bh][dh][s]
        #pragma unroll
        for (int h2 = 0; h2 < 2; ++h2) {
            if ((wave & 1) == h2) {
                #pragma unroll
                for (int i = 0; i < 4; ++i)
                    #pragma unroll
                    for (int j = 0; j < 4; ++j)
                        #pragma unroll
                        for (int r = 0; r < 4; ++r) {
                            int sl = wm + i * 16 + quad * 4 + r;   // 0..127
                            int dh = j * 16 + ln15;                // 0..63
                            SB[dh * 136 + sl] = f2bf(acc[i][j][r]);
                        }
            }
            __syncthreads();
            const int bh = b * H + (bn & 7) * 2 + h2;
            u16* dst = vtb + (size_t)bh * Dh * S + s0;
            for (int c = tid; c < 1024; c += 256) {
                int r = c >> 4, cc = (c & 15) * 8;
                *reinterpret_cast<bf16x8*>(&dst[(size_t)r * S + cc]) =
                    *reinterpret_cast<const bf16x8*>(&SB[r * 136 + cc]);
            }
            __syncthreads();
        }
    }
}

// ---------------------------------------------------------------------------
// Flash attention (causal) — round-8 structure (4 q-tiles {i,15-i,16+i,31-i},
// dbuf K/V, register-hoisted frags, fixed-offset softmax p=2^(s-24),
// P stride 72). Q fragments loaded directly from global (lane mapping
// verified identical to the old LDS-staged path).
// ---------------------------------------------------------------------------
__global__ __launch_bounds__(256) void attn_kernel(
    const u16* __restrict__ qbuf, const u16* __restrict__ kbuf,
    const u16* __restrict__ vt, u16* __restrict__ attno)
{
    const int i  = blockIdx.x;          // 0..7
    const int bh = blockIdx.y;          // 0..63
    const int b = bh >> 4, h = bh & 15;
    const int qt[4] = {i, 15 - i, 16 + i, 31 - i};

    __shared__ u16 Ks[2][64 * 64];
    __shared__ u16 Vs[2][64 * 64];      // [dh][kpos], chunk-swizzled
    __shared__ u16 Ps[4][16 * 72];      // per-wave P tile, stride 72

    const int tid  = threadIdx.x;
    const int wave = tid >> 6, ln = tid & 63;
    const int ln15 = ln & 15, quad = ln >> 4;
    const int swz  = ln15 & 7;

    const u16* kp0 = kbuf + (size_t)bh * S * Dh;
    const u16* vp0 = vt   + (size_t)bh * Dh * S;

    // Q fragments: direct global loads, pre-scaled by 0.125*log2e
    bf16x8 qf[4][2];
    #pragma unroll
    for (int t = 0; t < 4; ++t) {
        const u16* qp = qbuf + ((size_t)bh * S + qt[t] * 64 + wave * 16 + ln15) * Dh;
        #pragma unroll
        for (int st = 0; st < 2; ++st) {
            union { bf16x8 v; u16 u[8]; } in, ot;
            in.v = *reinterpret_cast<const bf16x8*>(&qp[st * 32 + quad * 8]);
            #pragma unroll
            for (int k = 0; k < 8; ++k) ot.u[k] = f2bf(bf2f(in.u[k]) * 0.18033688f);
            qf[t][st] = ot.v;
        }
    }

    float l_st[4][4] = {};
    f32x4 o_st[4][4] = {};

    u16* psw = &Ps[wave][0];
    const int lrow = wave * 16 + quad * 4;

    const int c0 = wave * 128 + ln;
    const int c1 = c0 + 64;
    const int kr0 = c0 >> 3, ko0 = (((c0 & 7) ^ (kr0 & 7)) * 8);
    const int kr1 = c1 >> 3, ko1 = (((c1 & 7) ^ (kr1 & 7)) * 8);

    auto stage = [&](int kblk, int buf) {
        llds16(kp0 + ((size_t)kblk * 64 + kr0) * Dh + ko0, &Ks[buf][(wave * 2 + 0) * 512]);
        llds16(kp0 + ((size_t)kblk * 64 + kr1) * Dh + ko1, &Ks[buf][(wave * 2 + 1) * 512]);
        llds16(vp0 + (size_t)kr0 * S + kblk * 64 + ko0,    &Vs[buf][(wave * 2 + 0) * 512]);
        llds16(vp0 + (size_t)kr1 * S + kblk * 64 + ko1,    &Vs[buf][(wave * 2 + 1) * 512]);
    };

    bf16x8 kf[2][4], vf[2][4];

    auto step = [&](int t, bool domask) {
        const bf16x8* qa = qf[t];
        float* l_r = l_st[t];
        f32x4* oa = o_st[t];
        f32x4 sf[4] = {};
        #pragma unroll
        for (int j = 0; j < 4; ++j) {
            sf[j] = mfma16(qa[0], kf[0][j], sf[j]);
            sf[j] = mfma16(qa[1], kf[1][j], sf[j]);
        }
        if (domask) {
            #pragma unroll
            for (int j = 0; j < 4; ++j) {
                int kg = j * 16 + ln15;
                #pragma unroll
                for (int r = 0; r < 4; ++r)
                    if (kg > lrow + r) sf[j][r] = -3e38f;
            }
        }
        #pragma unroll
        for (int j = 0; j < 4; ++j)
            #pragma unroll
            for (int r = 0; r < 4; ++r) {
                float p = exp2f(sf[j][r] - 24.0f);
                sf[j][r] = p;
                l_r[r] += p;
            }
        #pragma unroll
        for (int j = 0; j < 4; ++j)
            #pragma unroll
            for (int r = 0; r < 4; ++r)
                psw[(quad * 4 + r) * 72 + j * 16 + ln15] = f2bf(sf[j][r]);

        #pragma unroll
        for (int st = 0; st < 2; ++st) {
            bf16x8 pa = *reinterpret_cast<const bf16x8*>(&psw[ln15 * 72 + st * 32 + quad * 8]);
            #pragma unroll
            for (int jd = 0; jd < 4; ++jd)
                oa[jd] = mfma16(pa, vf[st][jd], oa[jd]);
        }
    };

    const int nstage = qt[3] + 1;       // 32 - i
    stage(0, 0);
    int cur = 0;
    for (int kblk = 0; kblk < nstage; ++kblk) {
        __syncthreads();                     // drains prefetch for cur buffer
        if (kblk + 1 < nstage) stage(kblk + 1, cur ^ 1);
        #pragma unroll
        for (int st = 0; st < 2; ++st)
            #pragma unroll
            for (int j = 0; j < 4; ++j) {
                kf[st][j] = *reinterpret_cast<const bf16x8*>(
                    &Ks[cur][(j * 16 + ln15) * 64 + ((st * 4 + quad) ^ swz) * 8]);
                vf[st][j] = *reinterpret_cast<const bf16x8*>(
                    &Vs[cur][(j * 16 + ln15) * 64 + ((st * 4 + quad) ^ swz) * 8]);
            }
        step(3, kblk == qt[3]);
        if (kblk <= qt[2]) step(2, kblk == qt[2]);
        if (kblk <= qt[1]) step(1, kblk == qt[1]);
        if (kblk <= qt[0]) step(0, kblk == qt[0]);
        cur ^= 1;
    }

    // epilogue: reduce l over the 16 column-lanes, divide, write token-major
    #pragma unroll
    for (int t = 0; t < 4; ++t) {
        float linv[4];
        #pragma unroll
        for (int r = 0; r < 4; ++r) {
            float l = l_st[t][r];
            l += __shfl_xor(l, 1, 64);
            l += __shfl_xor(l, 2, 64);
            l += __shfl_xor(l, 4, 64);
            l += __shfl_xor(l, 8, 64);
            linv[r] = 1.0f / l;
        }
        #pragma unroll
        for (int jd = 0; jd < 4; ++jd)
            #pragma unroll
            for (int r = 0; r < 4; ++r) {
                int qrow = qt[t] * 64 + wave * 16 + quad * 4 + r;
                size_t off = ((size_t)(b * S + qrow)) * D + h * Dh + jd * 16 + ln15;
                attno[off] = f2bf(o_st[t][jd][r] * linv[r]);
            }
    }
}

// ---------------------------------------------------------------------------
// 128x128 projection GEMM + bias, BK=64, swizzled staging: -> fp32 d_out
// ---------------------------------------------------------------------------
__global__ __launch_bounds__(256) void proj_gemm128(
    const u16* __restrict__ A, const u16* __restrict__ WoT,
    const float* __restrict__ bo, float* __restrict__ out)
{
    const int bm = blockIdx.x;     // 0..63
    const int bn = blockIdx.y;     // 0..7

    __shared__ u16 As[8192];
    __shared__ u16 Bs[8192];

    const int tid  = threadIdx.x;
    const int wave = tid >> 6, ln = tid & 63;
    const int ln15 = ln & 15, quad = ln >> 4;
    const int swz  = ln15 & 7;
    const int wm = (wave >> 1) * 64, wn = (wave & 1) * 64;

    const u16* Ab = A   + (size_t)(bm * 128) * D;
    const u16* Bb = WoT + (size_t)(bn * 128) * D;

    int srow[4], soff[4];
    #pragma unroll
    for (int k = 0; k < 4; ++k) {
        int ch = wave * 256 + k * 64 + ln;
        srow[k] = ch >> 3;
        soff[k] = ((ch & 7) ^ (srow[k] & 7)) * 8;
    }

    f32x4 acc[4][4] = {};

    for (int k0 = 0; k0 < D; k0 += 64) {
        __syncthreads();
        #pragma unroll
        for (int k = 0; k < 4; ++k) {
            llds16(Ab + (size_t)srow[k] * D + k0 + soff[k], &As[(wave * 4 + k) * 512]);
            llds16(Bb + (size_t)srow[k] * D + k0 + soff[k], &Bs[(wave * 4 + k) * 512]);
        }
        __syncthreads();
        #pragma unroll
        for (int ks = 0; ks < 2; ++ks) {
            bf16x8 af[4], bfr[4];
            #pragma unroll
            for (int i = 0; i < 4; ++i)
                af[i] = *reinterpret_cast<const bf16x8*>(
                    &As[(wm + i * 16 + ln15) * 64 + ((ks * 4 + quad) ^ swz) * 8]);
            #pragma unroll
            for (int j = 0; j < 4; ++j)
                bfr[j] = *reinterpret_cast<const bf16x8*>(
                    &Bs[(wn + j * 16 + ln15) * 64 + ((ks * 4 + quad) ^ swz) * 8]);
            #pragma unroll
            for (int i = 0; i < 4; ++i)
                #pragma unroll
                for (int j = 0; j < 4; ++j)
                    acc[i][j] = mfma16(af[i], bfr[j], acc[i][j]);
        }
    }

    #pragma unroll
    for (int i = 0; i < 4; ++i)
        #pragma unroll
        for (int j = 0; j < 4; ++j)
            #pragma unroll
            for (int r = 0; r < 4; ++r) {
                int t   = bm * 128 + wm + i * 16 + quad * 4 + r;
                int col = bn * 128 + wn + j * 16 + ln15;
                out[(size_t)t * D + col] = acc[i][j][r] + bo[col];
            }
}

extern "C" void kernel_launch(void* const* d_in, const int* in_sizes, int n_in,
                              void* d_out, int out_size, void* d_ws, size_t ws_size,
                              hipStream_t stream) {
    const float* x  = (const float*)d_in[0];
    const float* Wq = (const float*)d_in[1];
    const float* Wk = (const float*)d_in[2];
    const float* Wv = (const float*)d_in[3];
    const float* Wo = (const float*)d_in[4];
    const float* bo = (const float*)d_in[5];
    float* out = (float*)d_out;
    u16* ws  = (u16*)d_ws;

    u16* WT   = ws;                                   // 4M u16  (8 MB)
    u16* xb   = WT + (size_t)4 * D * D;               // 8M u16  (16 MB)
    u16* qkvb = xb + (size_t)M * D;                   // slots: Q, K, Vt (48 MB)
    u16* kb   = qkvb + (size_t)M * D;
    u16* vtb  = qkvb + (size_t)2 * M * D;             // V written transposed here
    u16* attn = xb;                                   // xb dead after qkv_gemm128

    prep        <<<dim3(16, 16, 20), 256, 0, stream>>>(x, Wq, Wk, Wv, Wo, WT, xb);
    qkv_gemm128 <<<dim3(64, 24),     256, 0, stream>>>(xb, WT, qkvb, vtb);
    attn_kernel <<<dim3(8, 64),      256, 0, stream>>>(qkvb, kb, vtb, attn);
    proj_gemm128<<<dim3(64, 8),      256, 0, stream>>>(attn, WT + (size_t)3 * D * D, bo, out);
}